// Round 4
// baseline (6015.692 us; speedup 1.0000x reference)
//
#include <hip/hip_runtime.h>

#define FHH 38
#define FWW 63
#define NPIX 2394        // 38*63
#define BATCH 8
#define CIN 1024
#define CMID 512
#define NSC 21546        // NPIX*9
#define M_TOT 19152      // BATCH*NPIX
#define K_TOT 9216       // CIN*9
#define PRE_N 2000
#define POST_N 300

typedef double f64x4 __attribute__((ext_vector_type(4)));

// exact anchors (generate_anchors(16,(0.5,1,2),(8,16,32))) — integer-valued, exact in any fp
__device__ const double ANCX1[9] = {-84.,-176.,-360.,-56.,-120.,-248.,-36.,-80.,-168.};
__device__ const double ANCY1[9] = {-40.,-88.,-184.,-56.,-120.,-248.,-80.,-168.,-344.};
__device__ const double ANCX2[9] = {99.,191.,375.,71.,135.,263.,51.,95.,183.};
__device__ const double ANCY2[9] = {55.,103.,199.,71.,135.,263.,95.,183.,359.};

// ---------------------------------------------------------------------------
// Probe kernel: derives the TRUE lane mapping of v_mfma_f64_16x16x4f64 at
// runtime (1 wave). Output tables (int):
//   tab[0..63]    a_row  (0..15)  A: which LDS row this lane's A value must come from
//   tab[64..127]  a_k    (0..3)   A: which k-slice
//   tab[128..191] b_k    (0..3)   B: which k-slice
//   tab[192..255] b_col  (0..15)  B: which column
//   tab[256..511] d_row[l*4+r]    D: row of acc reg r
//   tab[512..767] d_col[l*4+r]    D: col of acc reg r
// Correct for ANY bijective hardware layout: labels are class-mins ranked to
// 0..15 / 0..3; A-row<->D-row, B-col<->D-col, A-k<->B-k share label spaces, so
// the GEMM is invariant under the per-axis relabeling.
// ---------------------------------------------------------------------------
__global__ void mfma_probe_kernel(int* __restrict__ tab) {
    const int l = threadIdx.x;   // 64 lanes
    __shared__ int di[256], dj[256], ai[64], bj[64], ka[64], kb[64];
    __shared__ int shv;
    for (int r = 0; r < 4; ++r) { di[l * 4 + r] = -1; dj[l * 4 + r] = -1; }
    ai[l] = -1; bj[l] = -1; ka[l] = -1; kb[l] = 0x7fffffff;
    __syncthreads();
    const f64x4 zero = {0.0, 0.0, 0.0, 0.0};

    // probe 1: i-classes (A = delta_p, B = ones) -> lights D rows
    for (int p = 0; p < 64; ++p) {
        if (l == 0) shv = 0x7fffffff;
        __syncthreads();
        double a = (l == p) ? 1.0 : 0.0;
        f64x4 d = __builtin_amdgcn_mfma_f64_16x16x4f64(a, 1.0, zero, 0, 0, 0);
        bool lit[4];
#pragma unroll
        for (int r = 0; r < 4; ++r) lit[r] = (d[r] != 0.0);
#pragma unroll
        for (int r = 0; r < 4; ++r)
            if (lit[r]) atomicMin(&shv, di[l * 4 + r] < 0 ? p : di[l * 4 + r]);
        __syncthreads();
        int lab = shv;
#pragma unroll
        for (int r = 0; r < 4; ++r) if (lit[r]) di[l * 4 + r] = lab;
        if (l == p) ai[l] = lab;
        __syncthreads();
    }
    // probe 2: j-classes (A = ones, B = delta_q) -> lights D cols
    for (int q = 0; q < 64; ++q) {
        if (l == 0) shv = 0x7fffffff;
        __syncthreads();
        double b = (l == q) ? 1.0 : 0.0;
        f64x4 d = __builtin_amdgcn_mfma_f64_16x16x4f64(1.0, b, zero, 0, 0, 0);
        bool lit[4];
#pragma unroll
        for (int r = 0; r < 4; ++r) lit[r] = (d[r] != 0.0);
#pragma unroll
        for (int r = 0; r < 4; ++r)
            if (lit[r]) atomicMin(&shv, dj[l * 4 + r] < 0 ? q : dj[l * 4 + r]);
        __syncthreads();
        int lab = shv;
#pragma unroll
        for (int r = 0; r < 4; ++r) if (lit[r]) dj[l * 4 + r] = lab;
        if (l == q) bj[l] = lab;
        __syncthreads();
    }
    // probe 3: k-correspondence (A = delta_p, B lane q = 2^q) -> D = 2^q, q in k-class of p
    for (int p = 0; p < 64; ++p) {
        if (l == 0) shv = 0x7fffffff;
        __syncthreads();
        double a = (l == p) ? 1.0 : 0.0;
        double bv = __longlong_as_double((long long)(1023 + l) << 52);  // 2^l exact
        f64x4 d = __builtin_amdgcn_mfma_f64_16x16x4f64(a, bv, zero, 0, 0, 0);
        bool lit[4]; int qv[4];
#pragma unroll
        for (int r = 0; r < 4; ++r) {
            lit[r] = (d[r] != 0.0);
            qv[r] = lit[r] ? (((__double2hiint(d[r]) >> 20) & 0x7ff) - 1023) : 0;
        }
#pragma unroll
        for (int r = 0; r < 4; ++r) if (lit[r]) atomicMin(&shv, qv[r]);
        __syncthreads();
        int kmin = shv;
#pragma unroll
        for (int r = 0; r < 4; ++r) if (lit[r]) atomicMin(&kb[qv[r]], kmin);
        if (l == p) ka[l] = kmin;
        __syncthreads();
    }
    __syncthreads();
    // rank-compress labels and emit tables
    int a_row_rk = 0, a_k_rk = 0, b_k_rk = 0, b_col_rk = 0;
    for (int t = 0; t < 64; ++t) {
        a_row_rk += (ai[t] == t && t < ai[l]);
        b_col_rk += (bj[t] == t && t < bj[l]);
        a_k_rk   += (kb[t] == t && t < ka[l]);
        b_k_rk   += (kb[t] == t && t < kb[l]);
    }
    tab[l] = a_row_rk; tab[64 + l] = a_k_rk; tab[128 + l] = b_k_rk; tab[192 + l] = b_col_rk;
#pragma unroll
    for (int r = 0; r < 4; ++r) {
        int dr = 0, dc = 0;
        for (int t = 0; t < 64; ++t) {
            dr += (ai[t] == t && t < di[l * 4 + r]);
            dc += (bj[t] == t && t < dj[l * 4 + r]);
        }
        tab[256 + l * 4 + r] = dr;
        tab[512 + l * 4 + r] = dc;
    }
}

// K0: W_conv [512][1024][3][3] -> Wt[k][co], k=(kh*3+kw)*1024+ci   (fp32, exact copy)
__global__ void wt3x3_kernel(const float* __restrict__ W, float* __restrict__ Wt) {
    int gid = blockIdx.x * 256 + threadIdx.x;
    if (gid >= K_TOT * CMID) return;
    int co = gid & 511;
    int k  = gid >> 9;
    int pl = k >> 10;        // kh*3+kw
    int ci = k & 1023;
    Wt[gid] = W[((size_t)co * CIN + ci) * 9 + pl];
}

// K0b: W_cls[18][512], W_bbox[36][512] -> Wt2pD[k][64] double
__global__ void wt1x1_kernel(const float* __restrict__ Wc, const float* __restrict__ Wb,
                             double* __restrict__ Wt2pD) {
    int gid = blockIdx.x * 256 + threadIdx.x;
    if (gid >= CMID * 64) return;
    int n = gid & 63, k = gid >> 6;
    double v = 0.0;
    if (n < 18)      v = (double)Wc[(size_t)n * CMID + k];
    else if (n < 54) v = (double)Wb[(size_t)(n - 18) * CMID + k];
    Wt2pD[gid] = v;
}

// K1: implicit-GEMM 3x3 conv via probed FP64 MFMA + bias + relu.
// M=19152, N=512, K=9216. Block 64x128, BK=32, 4 waves (2m x 2n),
// wave tile 32x64 = 2x4 MFMA 16x16 tiles, fp64 LDS (48KB).
__global__ __launch_bounds__(256) void conv3x3_mfma(
    const float* __restrict__ x, const float* __restrict__ Wt,
    const float* __restrict__ bconv, const int* __restrict__ tab,
    double* __restrict__ feat) {
    __shared__ double As[32 * 64];   // [k][m] 16 KB
    __shared__ double Bs[32 * 128];  // [k][n] 32 KB
    const int tid = threadIdx.x;
    const int lane = tid & 63;
    const int wave = tid >> 6;       // 0..3
    const int wm = wave >> 1;        // m-offset 32*wm
    const int wn = wave & 1;         // n-offset 64*wn
    const int n0 = blockIdx.x * 128;
    const int m0 = blockIdx.y * 64;

    // probed layout tables
    const int aRow = tab[lane];
    const int aK   = tab[64 + lane];
    const int bK   = tab[128 + lane];
    const int bCol = tab[192 + lane];
    int dRow[4], dCol[4];
#pragma unroll
    for (int r = 0; r < 4; ++r) {
        dRow[r] = tab[256 + lane * 4 + r];
        dCol[r] = tab[512 + lane * 4 + r];
    }

    // staging thread mapping (identical to the verified R2 kernel)
    const int mm = tid & 63;
    const int t6 = tid >> 6;          // 0..3
    const int m = m0 + mm;
    const bool vm = (m < M_TOT);
    int b = 0, yy = 0, xx = 0;
    if (vm) { b = m / NPIX; int r = m - b * NPIX; yy = r / FWW; xx = r - yy * FWW; }
    const int bn_k = tid >> 5;        // 0..7
    const int bn_n = (tid & 31) << 2; // 0..124

    f64x4 acc[2][4];
#pragma unroll
    for (int i = 0; i < 2; ++i)
#pragma unroll
        for (int j = 0; j < 4; ++j) acc[i][j] = (f64x4){0.0, 0.0, 0.0, 0.0};

    const double* aBase = &As[(size_t)aK * 64 + wm * 32 + aRow];
    const double* bBase = &Bs[(size_t)bK * 128 + wn * 64 + bCol];

    for (int kc = 0; kc < 288; ++kc) {
        const int pl = kc >> 5;
        const int kh = pl / 3, kw = pl - kh * 3;
        const int ci0 = (kc & 31) << 5;
        const int iy = yy + kh - 1, ix = xx + kw - 1;
        const bool ok = vm && (iy >= 0) && (iy < FHH) && (ix >= 0) && (ix < FWW);
        const float* ap = x + ((size_t)(b * CIN + ci0 + t6)) * NPIX + iy * FWW + ix;
#pragma unroll
        for (int r = 0; r < 8; ++r) {
            float v = ok ? ap[(size_t)r * 4 * NPIX] : 0.f;
            As[(t6 + r * 4) * 64 + mm] = (double)v;
        }
        const int k0 = kc << 5;
        const float4* wp = (const float4*)(Wt + (size_t)(k0 + bn_k) * CMID + n0 + bn_n);
#pragma unroll
        for (int r = 0; r < 4; ++r) {
            float4 v = wp[(size_t)r * 1024];
            double* bd = &Bs[(bn_k + r * 8) * 128 + bn_n];
            bd[0] = (double)v.x; bd[1] = (double)v.y; bd[2] = (double)v.z; bd[3] = (double)v.w;
        }
        __syncthreads();
#pragma unroll
        for (int ks = 0; ks < 8; ++ks) {
            double a0 = aBase[ks * 256];
            double a1 = aBase[ks * 256 + 16];
            double b0 = bBase[ks * 512];
            double b1 = bBase[ks * 512 + 16];
            double b2 = bBase[ks * 512 + 32];
            double b3 = bBase[ks * 512 + 48];
            acc[0][0] = __builtin_amdgcn_mfma_f64_16x16x4f64(a0, b0, acc[0][0], 0, 0, 0);
            acc[0][1] = __builtin_amdgcn_mfma_f64_16x16x4f64(a0, b1, acc[0][1], 0, 0, 0);
            acc[0][2] = __builtin_amdgcn_mfma_f64_16x16x4f64(a0, b2, acc[0][2], 0, 0, 0);
            acc[0][3] = __builtin_amdgcn_mfma_f64_16x16x4f64(a0, b3, acc[0][3], 0, 0, 0);
            acc[1][0] = __builtin_amdgcn_mfma_f64_16x16x4f64(a1, b0, acc[1][0], 0, 0, 0);
            acc[1][1] = __builtin_amdgcn_mfma_f64_16x16x4f64(a1, b1, acc[1][1], 0, 0, 0);
            acc[1][2] = __builtin_amdgcn_mfma_f64_16x16x4f64(a1, b2, acc[1][2], 0, 0, 0);
            acc[1][3] = __builtin_amdgcn_mfma_f64_16x16x4f64(a1, b3, acc[1][3], 0, 0, 0);
        }
        __syncthreads();
    }
    // epilogue through probed D mapping
#pragma unroll
    for (int mi = 0; mi < 2; ++mi) {
#pragma unroll
        for (int nj = 0; nj < 4; ++nj) {
#pragma unroll
            for (int r = 0; r < 4; ++r) {
                int mg  = m0 + wm * 32 + mi * 16 + dRow[r];
                int col = n0 + wn * 64 + nj * 16 + dCol[r];
                if (mg < M_TOT)
                    feat[(size_t)mg * CMID + col] =
                        fmax(acc[mi][nj][r] + (double)bconv[col], 0.0);
            }
        }
    }
}

// K2: 1x1 convs (cls 18 + bbox 36 as 54 outputs), fp64. featD NHWC -> out54D[m][64]
__global__ __launch_bounds__(256) void conv1x1_kernel(
    const double* __restrict__ feat, const double* __restrict__ Wt2pD,
    const float* __restrict__ bcls, const float* __restrict__ bbx,
    double* __restrict__ out54) {
    __shared__ double As[4 * 512];
    __shared__ double Bsh[64 * 64];
    int tid = threadIdx.x;
    int m0 = blockIdx.x * 4;
    for (int off = tid; off < 2048; off += 256) As[off] = feat[(size_t)m0 * CMID + off];
    int p = tid >> 6, n = tid & 63;
    double acc = 0.0;
    for (int c = 0; c < 8; ++c) {
        __syncthreads();
        for (int off = tid; off < 4096; off += 256) Bsh[off] = Wt2pD[c * 4096 + off];
        __syncthreads();
        const double* ap = &As[p * 512 + c * 64];
#pragma unroll 8
        for (int k2 = 0; k2 < 64; ++k2) acc = fma(ap[k2], Bsh[k2 * 64 + n], acc);
    }
    if (n < 54) {
        double bias = (double)((n < 18) ? bcls[n] : bbx[n - 18]);
        out54[(size_t)(m0 + p) * 64 + n] = acc + bias;
    }
}

// K2b: softmax-pair score + bbox_transform_inv + clip, all fp64
__global__ void proposals_kernel(const double* __restrict__ out54, const float* __restrict__ iminfo,
                                 double* __restrict__ scoresD, double* __restrict__ propsD) {
    int gid = blockIdx.x * 256 + threadIdx.x;
    if (gid >= BATCH * NSC) return;
    int b = gid / NSC;
    int rem = gid - b * NSC;
    int p = rem / 9;
    int a = rem - p * 9;
    int y = p / FWW, x = p - y * FWW;
    int m = b * NPIX + p;
    const double* row = out54 + (size_t)m * 64;
    double s0 = row[a], s1 = row[9 + a];
    double mx = fmax(s0, s1);
    double e0 = exp(s0 - mx), e1 = exp(s1 - mx);
    scoresD[gid] = e1 / (e0 + e1);
    double dx = row[18 + 4 * a], dy = row[19 + 4 * a], dw = row[20 + 4 * a], dh = row[21 + 4 * a];
    double ax1 = x * 16.0 + ANCX1[a], ay1 = y * 16.0 + ANCY1[a];
    double ax2 = x * 16.0 + ANCX2[a], ay2 = y * 16.0 + ANCY2[a];
    double w = ax2 - ax1 + 1.0, h = ay2 - ay1 + 1.0;
    double cx = ax1 + 0.5 * w, cy = ay1 + 0.5 * h;
    double px = dx * w + cx, py = dy * h + cy;
    double pw = exp(dw) * w, ph = exp(dh) * h;
    double imh = (double)iminfo[b * 3 + 0], imw = (double)iminfo[b * 3 + 1];
    double x1 = fmin(fmax(px - 0.5 * pw, 0.0), imw - 1.0);
    double y1 = fmin(fmax(py - 0.5 * ph, 0.0), imh - 1.0);
    double x2 = fmin(fmax(px + 0.5 * pw, 0.0), imw - 1.0);
    double y2 = fmin(fmax(py + 0.5 * ph, 0.0), imh - 1.0);
    double* o = propsD + (size_t)gid * 4;
    o[0] = x1; o[1] = y1; o[2] = x2; o[3] = y2;
}

// K3: exact top-2000, stable lower-index ties. key = (double_score_bits & ~0x7FFF) | (~i & 0x7FFF)
__global__ __launch_bounds__(256) void select_kernel(const double* __restrict__ scoresD,
                                                     const double* __restrict__ propsD,
                                                     double* __restrict__ boxesD) {
    __shared__ unsigned int hist4[4][256];
    __shared__ unsigned int histf[256];
    __shared__ unsigned long long keys[2048];
    __shared__ unsigned long long sh_thr;
    __shared__ int sh_need;
    __shared__ int cnt;
    const int b = blockIdx.x, tid = threadIdx.x;
    const int w4 = tid >> 6;
    const double* sc = scoresD + (size_t)b * NSC;

    unsigned long long prefix = 0ull;
    int need = PRE_N;
    for (int d = 7; d >= 0; --d) {
        for (int z = tid; z < 1024; z += 256) ((unsigned int*)hist4)[z] = 0u;
        __syncthreads();
        const int shift = d * 8;
        const unsigned long long maskAbove = (d == 7) ? 0ull : (~0ull << (shift + 8));
        for (int i = tid; i < NSC; i += 256) {
            unsigned long long sb = (unsigned long long)__double_as_longlong(sc[i]);
            unsigned long long key = (sb & ~0x7FFFull) | (unsigned long long)((~i) & 0x7FFF);
            if (((key ^ prefix) & maskAbove) == 0ull)
                atomicAdd(&hist4[w4][(unsigned int)(key >> shift) & 255u], 1u);
        }
        __syncthreads();
        histf[tid] = hist4[0][tid] + hist4[1][tid] + hist4[2][tid] + hist4[3][tid];
        __syncthreads();
        if (tid == 0) {
            int acc = 0, v = 255;
            for (; v > 0; --v) {
                int c = (int)histf[v];
                if (acc + c >= need) break;
                acc += c;
            }
            sh_thr = prefix | ((unsigned long long)(unsigned int)v << shift);
            sh_need = need - acc;
        }
        __syncthreads();
        prefix = sh_thr;
        need = sh_need;
        __syncthreads();
    }
    if (tid == 0) cnt = 0;
    __syncthreads();
    for (int i = tid; i < NSC; i += 256) {
        unsigned long long sb = (unsigned long long)__double_as_longlong(sc[i]);
        unsigned long long key = (sb & ~0x7FFFull) | (unsigned long long)((~i) & 0x7FFF);
        if (key >= prefix) {
            int slot = atomicAdd(&cnt, 1);
            if (slot < 2048) keys[slot] = key;
        }
    }
    __syncthreads();
    int c0 = cnt;
    for (int i = tid; i < 2048; i += 256)
        if (i >= c0) keys[i] = 0ull;
    for (int k2 = 2; k2 <= 2048; k2 <<= 1)
        for (int j = k2 >> 1; j > 0; j >>= 1) {
            __syncthreads();
            for (int i = tid; i < 2048; i += 256) {
                int l = i ^ j;
                if (l > i) {
                    unsigned long long a = keys[i], c = keys[l];
                    bool up = (i & k2) == 0;
                    if (up ? (a < c) : (a > c)) { keys[i] = c; keys[l] = a; }
                }
            }
        }
    __syncthreads();
    const double* pr = propsD + (size_t)b * NSC * 4;
    double* bs = boxesD + (size_t)b * PRE_N * 4;
    for (int r = tid; r < PRE_N; r += 256) {
        int idx = (int)((~keys[r]) & 0x7FFF);
        if (idx >= NSC) idx = 0;
        bs[r * 4 + 0] = pr[(size_t)idx * 4 + 0];
        bs[r * 4 + 1] = pr[(size_t)idx * 4 + 1];
        bs[r * 4 + 2] = pr[(size_t)idx * 4 + 2];
        bs[r * 4 + 3] = pr[(size_t)idx * 4 + 3];
    }
}

// K4a: fp64 suppression bitmask. Interleaved: word w (0..31), bit t -> j = t*32 + w.
__global__ __launch_bounds__(256) void iou_mask_kernel(const double* __restrict__ boxesD,
                                                       unsigned long long* __restrict__ supmask) {
    __shared__ double bx[PRE_N * 4];
    int b = blockIdx.x;
    int i0 = blockIdx.y * 80;
    const double* src = boxesD + (size_t)b * PRE_N * 4;
    for (int o = threadIdx.x; o < PRE_N * 4; o += 256) bx[o] = src[o];
    __syncthreads();
    int ty = threadIdx.x >> 5, jw = threadIdx.x & 31;
    for (int ii = ty; ii < 80; ii += 8) {
        int i = i0 + ii;
        double bix1 = bx[i * 4 + 0], biy1 = bx[i * 4 + 1], bix2 = bx[i * 4 + 2], biy2 = bx[i * 4 + 3];
        double areai = (bix2 - bix1 + 1.0) * (biy2 - biy1 + 1.0);
        unsigned long long bits = 0ull;
        for (int t = 0; t < 64; ++t) {
            int j = t * 32 + jw;
            if (j > i && j < PRE_N) {
                double bjx1 = bx[j * 4 + 0], bjy1 = bx[j * 4 + 1], bjx2 = bx[j * 4 + 2], bjy2 = bx[j * 4 + 3];
                double iw = fmin(bix2, bjx2) - fmax(bix1, bjx1) + 1.0; iw = fmax(iw, 0.0);
                double ih = fmin(biy2, bjy2) - fmax(biy1, bjy1) + 1.0; ih = fmax(ih, 0.0);
                double inter = iw * ih;
                double areaj = (bjx2 - bjx1 + 1.0) * (bjy2 - bjy1 + 1.0);
                double iou = inter / (areai + areaj - inter);
                if (iou > 0.7) bits |= (1ull << t);
            }
        }
        supmask[((size_t)b * PRE_N + i) * 32 + jw] = bits;
    }
}

// K4b: sequential greedy suppression + first-300-kept (stable fill) + fp32 output
__global__ void nms_final_kernel(const unsigned long long* __restrict__ supmask,
                                 const double* __restrict__ boxesD,
                                 float* __restrict__ out) {
    int b = blockIdx.x;
    int lane = threadIdx.x;     // 64 threads
    int w = lane & 31;
    const unsigned long long* mask = supmask + (size_t)b * PRE_N * 32;
    int nbits = (w < 16) ? 63 : 62;
    unsigned long long kw = (1ull << nbits) - 1ull;
    unsigned long long rr[16];
#pragma unroll
    for (int d2 = 0; d2 < 16; ++d2) rr[d2] = mask[d2 * 32 + w];
    for (int i = 0; i < PRE_N; i += 16) {
#pragma unroll
        for (int u = 0; u < 16; ++u) {
            int ii = i + u;
            unsigned long long rcur = rr[u];
            int ip = ii + 16;
            rr[u] = (ip < PRE_N) ? mask[ip * 32 + w] : 0ull;
            unsigned long long kword = __shfl(kw, ii & 31);
            if ((kword >> (ii >> 5)) & 1ull) kw &= ~rcur;
        }
    }
    __shared__ unsigned long long keepw[32];
    __shared__ int pos[POST_N];
    if (lane < 32) keepw[lane] = kw;
    __syncthreads();
    if (lane == 0) {
        int c2 = 0;
        for (int j = 0; j < PRE_N && c2 < POST_N; ++j)
            if ((keepw[j & 31] >> (j >> 5)) & 1ull) pos[c2++] = j;
        for (int j = 0; j < PRE_N && c2 < POST_N; ++j)
            if (!((keepw[j & 31] >> (j >> 5)) & 1ull)) pos[c2++] = j;
    }
    __syncthreads();
    for (int r = lane; r < POST_N; r += 64) {
        int p = pos[r];
        const double* bxp = boxesD + ((size_t)b * PRE_N + p) * 4;
        float* o = out + ((size_t)b * POST_N + r) * 5;
        o[0] = (float)b; o[1] = (float)bxp[0]; o[2] = (float)bxp[1];
        o[3] = (float)bxp[2]; o[4] = (float)bxp[3];
    }
    if (b == 0 && lane == 0) { out[BATCH * POST_N * 5] = 0.f; out[BATCH * POST_N * 5 + 1] = 0.f; }
}

extern "C" void kernel_launch(void* const* d_in, const int* in_sizes, int n_in,
                              void* d_out, int out_size, void* d_ws, size_t ws_size,
                              hipStream_t stream) {
    (void)in_sizes; (void)n_in; (void)out_size; (void)ws_size;
    const float* base_feat = (const float*)d_in[0];
    const float* im_info   = (const float*)d_in[1];
    const float* W_conv    = (const float*)d_in[4];
    const float* b_conv    = (const float*)d_in[5];
    const float* W_cls     = (const float*)d_in[6];
    const float* b_cls     = (const float*)d_in[7];
    const float* W_bbox    = (const float*)d_in[8];
    const float* b_bbox    = (const float*)d_in[9];
    float* out = (float*)d_out;

    double* featD   = (double*)d_ws;            // 9,805,824 d
    double* out54D  = featD + 9805824;          // 1,225,728 d
    double* scoresD = out54D + 1225728;         //   172,368 d
    double* propsD  = scoresD + 172368;         //   689,472 d
    double* boxesD  = propsD + 689472;          //    64,000 d
    double* Wt2pD   = boxesD + 64000;           //    32,768 d
    unsigned long long* supmask = (unsigned long long*)(Wt2pD + 32768); // 512,000 u64
    float* Wt       = (float*)(supmask + 512000);                       // 4,718,592 f32
    // tab aliases the propsD region: written by probe (first), consumed by conv3x3,
    // then propsD is only written later by proposals_kernel — no overlap in lifetime.
    int* tab = (int*)propsD;                    // 768 ints

    mfma_probe_kernel<<<1, 64, 0, stream>>>(tab);
    wt3x3_kernel<<<(K_TOT * CMID + 255) / 256, 256, 0, stream>>>(W_conv, Wt);
    wt1x1_kernel<<<(CMID * 64 + 255) / 256, 256, 0, stream>>>(W_cls, W_bbox, Wt2pD);
    conv3x3_mfma<<<dim3(4, 300), 256, 0, stream>>>(base_feat, Wt, b_conv, tab, featD);
    conv1x1_kernel<<<M_TOT / 4, 256, 0, stream>>>(featD, Wt2pD, b_cls, b_bbox, out54D);
    proposals_kernel<<<(BATCH * NSC + 255) / 256, 256, 0, stream>>>(out54D, im_info, scoresD, propsD);
    select_kernel<<<BATCH, 256, 0, stream>>>(scoresD, propsD, boxesD);
    iou_mask_kernel<<<dim3(BATCH, 25), 256, 0, stream>>>(boxesD, supmask);
    nms_final_kernel<<<BATCH, 64, 0, stream>>>(supmask, boxesD, out);
}

// Round 5
// 4193.309 us; speedup vs baseline: 1.4346x; 1.4346x over previous
//
#include <hip/hip_runtime.h>

#define FHH 38
#define FWW 63
#define NPIX 2394        // 38*63
#define BATCH 8
#define CIN 1024
#define CMID 512
#define NSC 21546        // NPIX*9
#define M_TOT 19152      // BATCH*NPIX
#define K_TOT 9216       // CIN*9
#define PRE_N 2000
#define POST_N 300

typedef double f64x4 __attribute__((ext_vector_type(4)));

// exact anchors (generate_anchors(16,(0.5,1,2),(8,16,32))) — integer-valued, exact in any fp
__device__ const double ANCX1[9] = {-84.,-176.,-360.,-56.,-120.,-248.,-36.,-80.,-168.};
__device__ const double ANCY1[9] = {-40.,-88.,-184.,-56.,-120.,-248.,-80.,-168.,-344.};
__device__ const double ANCX2[9] = {99.,191.,375.,71.,135.,263.,51.,95.,183.};
__device__ const double ANCY2[9] = {55.,103.,199.,71.,135.,263.,95.,183.,359.};

// ---------------------------------------------------------------------------
// Probe: derives the TRUE lane mapping of v_mfma_f64_16x16x4f64 (1 wave,
// wave-level reductions only — no block atomics/barriers in the hot loops).
//   tab[0..63]    a_row (0..15)   tab[64..127]  a_k (0..3)
//   tab[128..191] b_k   (0..3)    tab[192..255] b_col (0..15)
//   tab[256..511] d_row[l*4+r]    tab[512..767] d_col[l*4+r]
// Probe 1 (64 iter): A=delta_p, B=2^lane -> lit regs give D-row classes;
//   exponent of D identifies the B lane -> k-correspondence for A and B.
// Probe 2 (64 iter): A=ones, B=delta_q -> lit regs give D-col classes.
// Labels = class-min lane, rank-compressed; GEMM invariant under per-axis
// bijective relabeling (A-row<->D-row, B-col<->D-col, A-k<->B-k shared).
// ---------------------------------------------------------------------------
__global__ void mfma_probe_kernel(int* __restrict__ tab) {
    const int l = threadIdx.x;   // 64 lanes
    __shared__ int aiS[64], bjS[64], kbS[64];
    const f64x4 zero = {0.0, 0.0, 0.0, 0.0};
    int di[4] = {-1, -1, -1, -1}, dj[4] = {-1, -1, -1, -1};
    int ai_l = 0, bj_l = 0, ka_l = 0;
    kbS[l] = 0x7fffffff;
    __syncthreads();

    const double bval = __longlong_as_double((long long)(1023 + l) << 52);  // 2^l exact
    for (int p = 0; p < 64; ++p) {
        double a = (l == p) ? 1.0 : 0.0;
        f64x4 d = __builtin_amdgcn_mfma_f64_16x16x4f64(a, bval, zero, 0, 0, 0);
        int lmin = 0x7fffffff, kmin = 0x7fffffff;
        bool lit[4]; int qv[4];
#pragma unroll
        for (int r = 0; r < 4; ++r) {
            lit[r] = (d[r] != 0.0);
            qv[r] = ((__double2hiint(d[r]) >> 20) & 0x7ff) - 1023;
            if (lit[r]) {
                lmin = min(lmin, di[r] < 0 ? p : di[r]);
                kmin = min(kmin, qv[r]);
            }
        }
#pragma unroll
        for (int off = 32; off > 0; off >>= 1) {
            lmin = min(lmin, __shfl_xor(lmin, off));
            kmin = min(kmin, __shfl_xor(kmin, off));
        }
#pragma unroll
        for (int r = 0; r < 4; ++r)
            if (lit[r]) { di[r] = lmin; atomicMin(&kbS[qv[r]], kmin); }
        if (l == p) { ai_l = lmin; ka_l = kmin; }
    }
    for (int q = 0; q < 64; ++q) {
        double b = (l == q) ? 1.0 : 0.0;
        f64x4 d = __builtin_amdgcn_mfma_f64_16x16x4f64(1.0, b, zero, 0, 0, 0);
        int lmin = 0x7fffffff;
        bool lit[4];
#pragma unroll
        for (int r = 0; r < 4; ++r) {
            lit[r] = (d[r] != 0.0);
            if (lit[r]) lmin = min(lmin, dj[r] < 0 ? q : dj[r]);
        }
#pragma unroll
        for (int off = 32; off > 0; off >>= 1) lmin = min(lmin, __shfl_xor(lmin, off));
#pragma unroll
        for (int r = 0; r < 4; ++r) if (lit[r]) dj[r] = lmin;
        if (l == q) bj_l = lmin;
    }
    aiS[l] = ai_l; bjS[l] = bj_l;
    __syncthreads();
    int kb_l = kbS[l];
    int a_row_rk = 0, a_k_rk = 0, b_k_rk = 0, b_col_rk = 0;
    for (int t = 0; t < 64; ++t) {
        a_row_rk += (aiS[t] == t && t < ai_l);
        b_col_rk += (bjS[t] == t && t < bj_l);
        a_k_rk   += (kbS[t] == t && t < ka_l);
        b_k_rk   += (kbS[t] == t && t < kb_l);
    }
    tab[l] = a_row_rk; tab[64 + l] = a_k_rk; tab[128 + l] = b_k_rk; tab[192 + l] = b_col_rk;
#pragma unroll
    for (int r = 0; r < 4; ++r) {
        int dr = 0, dc = 0;
        for (int t = 0; t < 64; ++t) {
            dr += (aiS[t] == t && t < di[r]);
            dc += (bjS[t] == t && t < dj[r]);
        }
        tab[256 + l * 4 + r] = dr;
        tab[512 + l * 4 + r] = dc;
    }
}

// K0: W_conv [512][1024][3][3] -> Wt[k][co], k=(kh*3+kw)*1024+ci   (fp32, exact copy)
__global__ void wt3x3_kernel(const float* __restrict__ W, float* __restrict__ Wt) {
    int gid = blockIdx.x * 256 + threadIdx.x;
    if (gid >= K_TOT * CMID) return;
    int co = gid & 511;
    int k  = gid >> 9;
    int pl = k >> 10;        // kh*3+kw
    int ci = k & 1023;
    Wt[gid] = W[((size_t)co * CIN + ci) * 9 + pl];
}

// K0b: W_cls[18][512], W_bbox[36][512] -> Wt2pD[k][64] double
__global__ void wt1x1_kernel(const float* __restrict__ Wc, const float* __restrict__ Wb,
                             double* __restrict__ Wt2pD) {
    int gid = blockIdx.x * 256 + threadIdx.x;
    if (gid >= CMID * 64) return;
    int n = gid & 63, k = gid >> 6;
    double v = 0.0;
    if (n < 18)      v = (double)Wc[(size_t)n * CMID + k];
    else if (n < 54) v = (double)Wb[(size_t)(n - 18) * CMID + k];
    Wt2pD[gid] = v;
}

// K1: implicit-GEMM 3x3 conv via probed FP64 MFMA + bias + relu.
// M=19152, N=512, K=9216. Block 64x64, BK=32, 4 waves (2m x 2n), wave 32x32.
// fp32 LDS tiles padded to 72 (2-way banks = free), cvt to fp64 at fragment
// load (inputs are exact fp32 -> products/accumulation identical to R2/R4).
__global__ __launch_bounds__(256, 4) void conv3x3_mfma(
    const float* __restrict__ x, const float* __restrict__ Wt,
    const float* __restrict__ bconv, const int* __restrict__ tab,
    double* __restrict__ feat) {
    __shared__ float As[32 * 72];   // [k][m]  9.2 KB
    __shared__ float Bs[32 * 72];   // [k][n]  9.2 KB
    const int tid = threadIdx.x;
    const int lane = tid & 63;
    const int wave = tid >> 6;       // 0..3
    const int wm = wave >> 1;        // m-offset 32*wm
    const int wn = wave & 1;         // n-offset 32*wn
    const int n0 = blockIdx.x * 64;
    const int m0 = blockIdx.y * 64;

    const int aRow = tab[lane];
    const int aK   = tab[64 + lane];
    const int bK   = tab[128 + lane];
    const int bCol = tab[192 + lane];
    int dRow[4], dCol[4];
#pragma unroll
    for (int r = 0; r < 4; ++r) {
        dRow[r] = tab[256 + lane * 4 + r];
        dCol[r] = tab[512 + lane * 4 + r];
    }

    // A staging mapping (identical indexing to the verified R2/R4 kernels)
    const int mm = tid & 63;
    const int t6 = tid >> 6;          // 0..3
    const int m = m0 + mm;
    const bool vm = (m < M_TOT);
    int b = 0, yy = 0, xx = 0;
    if (vm) { b = m / NPIX; int r = m - b * NPIX; yy = r / FWW; xx = r - yy * FWW; }
    // B staging: 32x64 floats, 8 per thread (2x float4)
    const int bk2 = tid >> 4;         // 0..15
    const int bn2 = (tid & 15) << 2;  // 0..60

    f64x4 acc[2][2];
#pragma unroll
    for (int i = 0; i < 2; ++i)
#pragma unroll
        for (int j = 0; j < 2; ++j) acc[i][j] = (f64x4){0.0, 0.0, 0.0, 0.0};

    const float* aBase = &As[aK * 72 + wm * 32 + aRow];
    const float* bBase = &Bs[bK * 72 + wn * 32 + bCol];

    for (int kc = 0; kc < 288; ++kc) {
        const int pl = kc >> 5;
        const int kh = pl / 3, kw = pl - kh * 3;
        const int ci0 = (kc & 31) << 5;
        const int iy = yy + kh - 1, ix = xx + kw - 1;
        const bool ok = vm && (iy >= 0) && (iy < FHH) && (ix >= 0) && (ix < FWW);
        const float* ap = x + ((size_t)(b * CIN + ci0 + t6)) * NPIX + iy * FWW + ix;
#pragma unroll
        for (int r = 0; r < 8; ++r) {
            float v = ok ? ap[(size_t)r * 4 * NPIX] : 0.f;
            As[(t6 + r * 4) * 72 + mm] = v;
        }
        const int k0 = kc << 5;
        const float4* wp = (const float4*)(Wt + (size_t)(k0 + bk2) * CMID + n0 + bn2);
        float4 v0 = wp[0];
        float4 v1 = wp[2048];   // +16 rows * 512 floats
        *(float4*)&Bs[bk2 * 72 + bn2] = v0;
        *(float4*)&Bs[(bk2 + 16) * 72 + bn2] = v1;
        __syncthreads();
#pragma unroll
        for (int ks = 0; ks < 8; ++ks) {
            double a0 = (double)aBase[ks * 288];        // (ks*4)*72
            double a1 = (double)aBase[ks * 288 + 16];
            double b0 = (double)bBase[ks * 288];
            double b1 = (double)bBase[ks * 288 + 16];
            acc[0][0] = __builtin_amdgcn_mfma_f64_16x16x4f64(a0, b0, acc[0][0], 0, 0, 0);
            acc[0][1] = __builtin_amdgcn_mfma_f64_16x16x4f64(a0, b1, acc[0][1], 0, 0, 0);
            acc[1][0] = __builtin_amdgcn_mfma_f64_16x16x4f64(a1, b0, acc[1][0], 0, 0, 0);
            acc[1][1] = __builtin_amdgcn_mfma_f64_16x16x4f64(a1, b1, acc[1][1], 0, 0, 0);
        }
        __syncthreads();
    }
    // epilogue through probed D mapping
#pragma unroll
    for (int mi = 0; mi < 2; ++mi) {
#pragma unroll
        for (int nj = 0; nj < 2; ++nj) {
#pragma unroll
            for (int r = 0; r < 4; ++r) {
                int mg  = m0 + wm * 32 + mi * 16 + dRow[r];
                int col = n0 + wn * 32 + nj * 16 + dCol[r];
                if (mg < M_TOT)
                    feat[(size_t)mg * CMID + col] =
                        fmax(acc[mi][nj][r] + (double)bconv[col], 0.0);
            }
        }
    }
}

// K2: 1x1 convs (cls 18 + bbox 36 as 54 outputs), fp64. featD NHWC -> out54D[m][64]
__global__ __launch_bounds__(256) void conv1x1_kernel(
    const double* __restrict__ feat, const double* __restrict__ Wt2pD,
    const float* __restrict__ bcls, const float* __restrict__ bbx,
    double* __restrict__ out54) {
    __shared__ double As[4 * 512];
    __shared__ double Bsh[64 * 64];
    int tid = threadIdx.x;
    int m0 = blockIdx.x * 4;
    for (int off = tid; off < 2048; off += 256) As[off] = feat[(size_t)m0 * CMID + off];
    int p = tid >> 6, n = tid & 63;
    double acc = 0.0;
    for (int c = 0; c < 8; ++c) {
        __syncthreads();
        for (int off = tid; off < 4096; off += 256) Bsh[off] = Wt2pD[c * 4096 + off];
        __syncthreads();
        const double* ap = &As[p * 512 + c * 64];
#pragma unroll 8
        for (int k2 = 0; k2 < 64; ++k2) acc = fma(ap[k2], Bsh[k2 * 64 + n], acc);
    }
    if (n < 54) {
        double bias = (double)((n < 18) ? bcls[n] : bbx[n - 18]);
        out54[(size_t)(m0 + p) * 64 + n] = acc + bias;
    }
}

// K2b: softmax-pair score + bbox_transform_inv + clip, all fp64
__global__ void proposals_kernel(const double* __restrict__ out54, const float* __restrict__ iminfo,
                                 double* __restrict__ scoresD, double* __restrict__ propsD) {
    int gid = blockIdx.x * 256 + threadIdx.x;
    if (gid >= BATCH * NSC) return;
    int b = gid / NSC;
    int rem = gid - b * NSC;
    int p = rem / 9;
    int a = rem - p * 9;
    int y = p / FWW, x = p - y * FWW;
    int m = b * NPIX + p;
    const double* row = out54 + (size_t)m * 64;
    double s0 = row[a], s1 = row[9 + a];
    double mx = fmax(s0, s1);
    double e0 = exp(s0 - mx), e1 = exp(s1 - mx);
    scoresD[gid] = e1 / (e0 + e1);
    double dx = row[18 + 4 * a], dy = row[19 + 4 * a], dw = row[20 + 4 * a], dh = row[21 + 4 * a];
    double ax1 = x * 16.0 + ANCX1[a], ay1 = y * 16.0 + ANCY1[a];
    double ax2 = x * 16.0 + ANCX2[a], ay2 = y * 16.0 + ANCY2[a];
    double w = ax2 - ax1 + 1.0, h = ay2 - ay1 + 1.0;
    double cx = ax1 + 0.5 * w, cy = ay1 + 0.5 * h;
    double px = dx * w + cx, py = dy * h + cy;
    double pw = exp(dw) * w, ph = exp(dh) * h;
    double imh = (double)iminfo[b * 3 + 0], imw = (double)iminfo[b * 3 + 1];
    double x1 = fmin(fmax(px - 0.5 * pw, 0.0), imw - 1.0);
    double y1 = fmin(fmax(py - 0.5 * ph, 0.0), imh - 1.0);
    double x2 = fmin(fmax(px + 0.5 * pw, 0.0), imw - 1.0);
    double y2 = fmin(fmax(py + 0.5 * ph, 0.0), imh - 1.0);
    double* o = propsD + (size_t)gid * 4;
    o[0] = x1; o[1] = y1; o[2] = x2; o[3] = y2;
}

// K3: exact top-2000, stable lower-index ties. key = (double_score_bits & ~0x7FFF) | (~i & 0x7FFF)
__global__ __launch_bounds__(256) void select_kernel(const double* __restrict__ scoresD,
                                                     const double* __restrict__ propsD,
                                                     double* __restrict__ boxesD) {
    __shared__ unsigned int hist4[4][256];
    __shared__ unsigned int histf[256];
    __shared__ unsigned long long keys[2048];
    __shared__ unsigned long long sh_thr;
    __shared__ int sh_need;
    __shared__ int cnt;
    const int b = blockIdx.x, tid = threadIdx.x;
    const int w4 = tid >> 6;
    const double* sc = scoresD + (size_t)b * NSC;

    unsigned long long prefix = 0ull;
    int need = PRE_N;
    for (int d = 7; d >= 0; --d) {
        for (int z = tid; z < 1024; z += 256) ((unsigned int*)hist4)[z] = 0u;
        __syncthreads();
        const int shift = d * 8;
        const unsigned long long maskAbove = (d == 7) ? 0ull : (~0ull << (shift + 8));
        for (int i = tid; i < NSC; i += 256) {
            unsigned long long sb = (unsigned long long)__double_as_longlong(sc[i]);
            unsigned long long key = (sb & ~0x7FFFull) | (unsigned long long)((~i) & 0x7FFF);
            if (((key ^ prefix) & maskAbove) == 0ull)
                atomicAdd(&hist4[w4][(unsigned int)(key >> shift) & 255u], 1u);
        }
        __syncthreads();
        histf[tid] = hist4[0][tid] + hist4[1][tid] + hist4[2][tid] + hist4[3][tid];
        __syncthreads();
        if (tid == 0) {
            int acc = 0, v = 255;
            for (; v > 0; --v) {
                int c = (int)histf[v];
                if (acc + c >= need) break;
                acc += c;
            }
            sh_thr = prefix | ((unsigned long long)(unsigned int)v << shift);
            sh_need = need - acc;
        }
        __syncthreads();
        prefix = sh_thr;
        need = sh_need;
        __syncthreads();
    }
    if (tid == 0) cnt = 0;
    __syncthreads();
    for (int i = tid; i < NSC; i += 256) {
        unsigned long long sb = (unsigned long long)__double_as_longlong(sc[i]);
        unsigned long long key = (sb & ~0x7FFFull) | (unsigned long long)((~i) & 0x7FFF);
        if (key >= prefix) {
            int slot = atomicAdd(&cnt, 1);
            if (slot < 2048) keys[slot] = key;
        }
    }
    __syncthreads();
    int c0 = cnt;
    for (int i = tid; i < 2048; i += 256)
        if (i >= c0) keys[i] = 0ull;
    for (int k2 = 2; k2 <= 2048; k2 <<= 1)
        for (int j = k2 >> 1; j > 0; j >>= 1) {
            __syncthreads();
            for (int i = tid; i < 2048; i += 256) {
                int l = i ^ j;
                if (l > i) {
                    unsigned long long a = keys[i], c = keys[l];
                    bool up = (i & k2) == 0;
                    if (up ? (a < c) : (a > c)) { keys[i] = c; keys[l] = a; }
                }
            }
        }
    __syncthreads();
    const double* pr = propsD + (size_t)b * NSC * 4;
    double* bs = boxesD + (size_t)b * PRE_N * 4;
    for (int r = tid; r < PRE_N; r += 256) {
        int idx = (int)((~keys[r]) & 0x7FFF);
        if (idx >= NSC) idx = 0;
        bs[r * 4 + 0] = pr[(size_t)idx * 4 + 0];
        bs[r * 4 + 1] = pr[(size_t)idx * 4 + 1];
        bs[r * 4 + 2] = pr[(size_t)idx * 4 + 2];
        bs[r * 4 + 3] = pr[(size_t)idx * 4 + 3];
    }
}

// K4a: fp64 suppression bitmask. Interleaved: word w (0..31), bit t -> j = t*32 + w.
__global__ __launch_bounds__(256) void iou_mask_kernel(const double* __restrict__ boxesD,
                                                       unsigned long long* __restrict__ supmask) {
    __shared__ double bx[PRE_N * 4];
    int b = blockIdx.x;
    int i0 = blockIdx.y * 80;
    const double* src = boxesD + (size_t)b * PRE_N * 4;
    for (int o = threadIdx.x; o < PRE_N * 4; o += 256) bx[o] = src[o];
    __syncthreads();
    int ty = threadIdx.x >> 5, jw = threadIdx.x & 31;
    for (int ii = ty; ii < 80; ii += 8) {
        int i = i0 + ii;
        double bix1 = bx[i * 4 + 0], biy1 = bx[i * 4 + 1], bix2 = bx[i * 4 + 2], biy2 = bx[i * 4 + 3];
        double areai = (bix2 - bix1 + 1.0) * (biy2 - biy1 + 1.0);
        unsigned long long bits = 0ull;
        for (int t = 0; t < 64; ++t) {
            int j = t * 32 + jw;
            if (j > i && j < PRE_N) {
                double bjx1 = bx[j * 4 + 0], bjy1 = bx[j * 4 + 1], bjx2 = bx[j * 4 + 2], bjy2 = bx[j * 4 + 3];
                double iw = fmin(bix2, bjx2) - fmax(bix1, bjx1) + 1.0; iw = fmax(iw, 0.0);
                double ih = fmin(biy2, bjy2) - fmax(biy1, bjy1) + 1.0; ih = fmax(ih, 0.0);
                double inter = iw * ih;
                double areaj = (bjx2 - bjx1 + 1.0) * (bjy2 - bjy1 + 1.0);
                double iou = inter / (areai + areaj - inter);
                if (iou > 0.7) bits |= (1ull << t);
            }
        }
        supmask[((size_t)b * PRE_N + i) * 32 + jw] = bits;
    }
}

// K4b: sequential greedy suppression + first-300-kept (stable fill) + fp32 output
__global__ void nms_final_kernel(const unsigned long long* __restrict__ supmask,
                                 const double* __restrict__ boxesD,
                                 float* __restrict__ out) {
    int b = blockIdx.x;
    int lane = threadIdx.x;     // 64 threads
    int w = lane & 31;
    const unsigned long long* mask = supmask + (size_t)b * PRE_N * 32;
    int nbits = (w < 16) ? 63 : 62;
    unsigned long long kw = (1ull << nbits) - 1ull;
    unsigned long long rr[16];
#pragma unroll
    for (int d2 = 0; d2 < 16; ++d2) rr[d2] = mask[d2 * 32 + w];
    for (int i = 0; i < PRE_N; i += 16) {
#pragma unroll
        for (int u = 0; u < 16; ++u) {
            int ii = i + u;
            unsigned long long rcur = rr[u];
            int ip = ii + 16;
            rr[u] = (ip < PRE_N) ? mask[ip * 32 + w] : 0ull;
            unsigned long long kword = __shfl(kw, ii & 31);
            if ((kword >> (ii >> 5)) & 1ull) kw &= ~rcur;
        }
    }
    __shared__ unsigned long long keepw[32];
    __shared__ int pos[POST_N];
    if (lane < 32) keepw[lane] = kw;
    __syncthreads();
    if (lane == 0) {
        int c2 = 0;
        for (int j = 0; j < PRE_N && c2 < POST_N; ++j)
            if ((keepw[j & 31] >> (j >> 5)) & 1ull) pos[c2++] = j;
        for (int j = 0; j < PRE_N && c2 < POST_N; ++j)
            if (!((keepw[j & 31] >> (j >> 5)) & 1ull)) pos[c2++] = j;
    }
    __syncthreads();
    for (int r = lane; r < POST_N; r += 64) {
        int p = pos[r];
        const double* bxp = boxesD + ((size_t)b * PRE_N + p) * 4;
        float* o = out + ((size_t)b * POST_N + r) * 5;
        o[0] = (float)b; o[1] = (float)bxp[0]; o[2] = (float)bxp[1];
        o[3] = (float)bxp[2]; o[4] = (float)bxp[3];
    }
    if (b == 0 && lane == 0) { out[BATCH * POST_N * 5] = 0.f; out[BATCH * POST_N * 5 + 1] = 0.f; }
}

extern "C" void kernel_launch(void* const* d_in, const int* in_sizes, int n_in,
                              void* d_out, int out_size, void* d_ws, size_t ws_size,
                              hipStream_t stream) {
    (void)in_sizes; (void)n_in; (void)out_size; (void)ws_size;
    const float* base_feat = (const float*)d_in[0];
    const float* im_info   = (const float*)d_in[1];
    const float* W_conv    = (const float*)d_in[4];
    const float* b_conv    = (const float*)d_in[5];
    const float* W_cls     = (const float*)d_in[6];
    const float* b_cls     = (const float*)d_in[7];
    const float* W_bbox    = (const float*)d_in[8];
    const float* b_bbox    = (const float*)d_in[9];
    float* out = (float*)d_out;

    double* featD   = (double*)d_ws;            // 9,805,824 d
    double* out54D  = featD + 9805824;          // 1,225,728 d
    double* scoresD = out54D + 1225728;         //   172,368 d
    double* propsD  = scoresD + 172368;         //   689,472 d
    double* boxesD  = propsD + 689472;          //    64,000 d
    double* Wt2pD   = boxesD + 64000;           //    32,768 d
    unsigned long long* supmask = (unsigned long long*)(Wt2pD + 32768); // 512,000 u64
    float* Wt       = (float*)(supmask + 512000);                       // 4,718,592 f32
    // tab aliases propsD: probe writes it first; conv3x3 consumes it; propsD is
    // only written later by proposals_kernel — disjoint lifetimes.
    int* tab = (int*)propsD;                    // 768 ints

    mfma_probe_kernel<<<1, 64, 0, stream>>>(tab);
    wt3x3_kernel<<<(K_TOT * CMID + 255) / 256, 256, 0, stream>>>(W_conv, Wt);
    wt1x1_kernel<<<(CMID * 64 + 255) / 256, 256, 0, stream>>>(W_cls, W_bbox, Wt2pD);
    conv3x3_mfma<<<dim3(8, 300), 256, 0, stream>>>(base_feat, Wt, b_conv, tab, featD);
    conv1x1_kernel<<<M_TOT / 4, 256, 0, stream>>>(featD, Wt2pD, b_cls, b_bbox, out54D);
    proposals_kernel<<<(BATCH * NSC + 255) / 256, 256, 0, stream>>>(out54D, im_info, scoresD, propsD);
    select_kernel<<<BATCH, 256, 0, stream>>>(scoresD, propsD, boxesD);
    iou_mask_kernel<<<dim3(BATCH, 25), 256, 0, stream>>>(boxesD, supmask);
    nms_final_kernel<<<BATCH, 64, 0, stream>>>(supmask, boxesD, out);
}

// Round 6
// 4074.326 us; speedup vs baseline: 1.4765x; 1.0292x over previous
//
#include <hip/hip_runtime.h>

#define FHH 38
#define FWW 63
#define NPIX 2394        // 38*63
#define BATCH 8
#define CIN 1024
#define CMID 512
#define NSC 21546        // NPIX*9
#define M_TOT 19152      // BATCH*NPIX
#define K_TOT 9216       // CIN*9
#define PRE_N 2000
#define POST_N 300

typedef double f64x4 __attribute__((ext_vector_type(4)));

// exact anchors (generate_anchors(16,(0.5,1,2),(8,16,32))) — integer-valued, exact in any fp
__device__ const double ANCX1[9] = {-84.,-176.,-360.,-56.,-120.,-248.,-36.,-80.,-168.};
__device__ const double ANCY1[9] = {-40.,-88.,-184.,-56.,-120.,-248.,-80.,-168.,-344.};
__device__ const double ANCX2[9] = {99.,191.,375.,71.,135.,263.,51.,95.,183.};
__device__ const double ANCY2[9] = {55.,103.,199.,71.,135.,263.,95.,183.,359.};

// ---------------------------------------------------------------------------
// Probe: derives the TRUE lane mapping of v_mfma_f64_16x16x4f64 (1 wave).
// tab[0..63] a_row | [64..127] a_k | [128..191] b_k | [192..255] b_col
// [256..511] d_row[l*4+r] | [512..767] d_col[l*4+r]
// ---------------------------------------------------------------------------
__global__ void mfma_probe_kernel(int* __restrict__ tab) {
    const int l = threadIdx.x;   // 64 lanes
    __shared__ int aiS[64], bjS[64], kbS[64];
    const f64x4 zero = {0.0, 0.0, 0.0, 0.0};
    int di[4] = {-1, -1, -1, -1}, dj[4] = {-1, -1, -1, -1};
    int ai_l = 0, bj_l = 0, ka_l = 0;
    kbS[l] = 0x7fffffff;
    __syncthreads();

    const double bval = __longlong_as_double((long long)(1023 + l) << 52);  // 2^l exact
    for (int p = 0; p < 64; ++p) {
        double a = (l == p) ? 1.0 : 0.0;
        f64x4 d = __builtin_amdgcn_mfma_f64_16x16x4f64(a, bval, zero, 0, 0, 0);
        int lmin = 0x7fffffff, kmin = 0x7fffffff;
        bool lit[4]; int qv[4];
#pragma unroll
        for (int r = 0; r < 4; ++r) {
            lit[r] = (d[r] != 0.0);
            qv[r] = ((__double2hiint(d[r]) >> 20) & 0x7ff) - 1023;
            if (lit[r]) {
                lmin = min(lmin, di[r] < 0 ? p : di[r]);
                kmin = min(kmin, qv[r]);
            }
        }
#pragma unroll
        for (int off = 32; off > 0; off >>= 1) {
            lmin = min(lmin, __shfl_xor(lmin, off));
            kmin = min(kmin, __shfl_xor(kmin, off));
        }
#pragma unroll
        for (int r = 0; r < 4; ++r)
            if (lit[r]) { di[r] = lmin; atomicMin(&kbS[qv[r]], kmin); }
        if (l == p) { ai_l = lmin; ka_l = kmin; }
    }
    for (int q = 0; q < 64; ++q) {
        double b = (l == q) ? 1.0 : 0.0;
        f64x4 d = __builtin_amdgcn_mfma_f64_16x16x4f64(1.0, b, zero, 0, 0, 0);
        int lmin = 0x7fffffff;
        bool lit[4];
#pragma unroll
        for (int r = 0; r < 4; ++r) {
            lit[r] = (d[r] != 0.0);
            if (lit[r]) lmin = min(lmin, dj[r] < 0 ? q : dj[r]);
        }
#pragma unroll
        for (int off = 32; off > 0; off >>= 1) lmin = min(lmin, __shfl_xor(lmin, off));
#pragma unroll
        for (int r = 0; r < 4; ++r) if (lit[r]) dj[r] = lmin;
        if (l == q) bj_l = lmin;
    }
    aiS[l] = ai_l; bjS[l] = bj_l;
    __syncthreads();
    int kb_l = kbS[l];
    int a_row_rk = 0, a_k_rk = 0, b_k_rk = 0, b_col_rk = 0;
    for (int t = 0; t < 64; ++t) {
        a_row_rk += (aiS[t] == t && t < ai_l);
        b_col_rk += (bjS[t] == t && t < bj_l);
        a_k_rk   += (kbS[t] == t && t < ka_l);
        b_k_rk   += (kbS[t] == t && t < kb_l);
    }
    tab[l] = a_row_rk; tab[64 + l] = a_k_rk; tab[128 + l] = b_k_rk; tab[192 + l] = b_col_rk;
#pragma unroll
    for (int r = 0; r < 4; ++r) {
        int dr = 0, dc = 0;
        for (int t = 0; t < 64; ++t) {
            dr += (aiS[t] == t && t < di[r]);
            dc += (bjS[t] == t && t < dj[r]);
        }
        tab[256 + l * 4 + r] = dr;
        tab[512 + l * 4 + r] = dc;
    }
}

// K0: W_conv [512][1024][3][3] -> Wt[k][co], k=(kh*3+kw)*1024+ci   (fp32, exact copy)
__global__ void wt3x3_kernel(const float* __restrict__ W, float* __restrict__ Wt) {
    int gid = blockIdx.x * 256 + threadIdx.x;
    if (gid >= K_TOT * CMID) return;
    int co = gid & 511;
    int k  = gid >> 9;
    int pl = k >> 10;        // kh*3+kw
    int ci = k & 1023;
    Wt[gid] = W[((size_t)co * CIN + ci) * 9 + pl];
}

// K0b: W_cls[18][512], W_bbox[36][512] -> Wt2pD[k][64] double
__global__ void wt1x1_kernel(const float* __restrict__ Wc, const float* __restrict__ Wb,
                             double* __restrict__ Wt2pD) {
    int gid = blockIdx.x * 256 + threadIdx.x;
    if (gid >= CMID * 64) return;
    int n = gid & 63, k = gid >> 6;
    double v = 0.0;
    if (n < 18)      v = (double)Wc[(size_t)n * CMID + k];
    else if (n < 54) v = (double)Wb[(size_t)(n - 18) * CMID + k];
    Wt2pD[gid] = v;
}

// K1: implicit-GEMM 3x3 conv via probed FP64 MFMA + bias + relu.
// M=19152, N=512, K=9216. Block 64x64, BK=32, 4 waves (2m x 2n), wave 32x32.
// DOUBLE-BUFFERED fp32 LDS tiles (2x18KB, padded stride 72) with T14 split:
// issue next-tile global loads -> MFMA current buffer -> write regs->LDS other
// buffer -> ONE barrier per kc step. Numerics identical (exact fp32 staging,
// fp64 MFMA accumulation).
#define ASZ (32 * 72)
__global__ __launch_bounds__(256, 4) void conv3x3_mfma(
    const float* __restrict__ x, const float* __restrict__ Wt,
    const float* __restrict__ bconv, const int* __restrict__ tab,
    double* __restrict__ feat) {
    __shared__ float As[2 * ASZ];   // [buf][k][m]  18.4 KB
    __shared__ float Bs[2 * ASZ];   // [buf][k][n]  18.4 KB
    const int tid = threadIdx.x;
    const int lane = tid & 63;
    const int wave = tid >> 6;       // 0..3
    const int wm = wave >> 1;        // m-offset 32*wm
    const int wn = wave & 1;         // n-offset 32*wn
    const int n0 = blockIdx.x * 64;
    const int m0 = blockIdx.y * 64;

    const int aRow = tab[lane];
    const int aK   = tab[64 + lane];
    const int bK   = tab[128 + lane];
    const int bCol = tab[192 + lane];
    int dRow[4], dCol[4];
#pragma unroll
    for (int r = 0; r < 4; ++r) {
        dRow[r] = tab[256 + lane * 4 + r];
        dCol[r] = tab[512 + lane * 4 + r];
    }

    // A staging mapping (indexing identical to the verified R2/R4/R5 kernels)
    const int mm = tid & 63;
    const int t6 = tid >> 6;          // 0..3
    const int m = m0 + mm;
    const bool vm = (m < M_TOT);
    int b = 0, yy = 0, xx = 0;
    if (vm) { b = m / NPIX; int r = m - b * NPIX; yy = r / FWW; xx = r - yy * FWW; }
    // B staging: 32x64 floats, 8 per thread (2x float4)
    const int bk2 = tid >> 4;         // 0..15
    const int bn2 = (tid & 15) << 2;  // 0..60

    f64x4 acc[2][2];
#pragma unroll
    for (int i = 0; i < 2; ++i)
#pragma unroll
        for (int j = 0; j < 2; ++j) acc[i][j] = (f64x4){0.0, 0.0, 0.0, 0.0};

    const float* aBase = &As[aK * 72 + wm * 32 + aRow];
    const float* bBase = &Bs[bK * 72 + wn * 32 + bCol];

    // ---- staging helpers (macros keep buffer index compile-time) ----
#define STAGE_REGS(KC, VA, VB0, VB1) do {                                     \
        const int pl_ = (KC) >> 5;                                            \
        const int kh_ = pl_ / 3, kw_ = pl_ - kh_ * 3;                         \
        const int ci0_ = ((KC) & 31) << 5;                                    \
        const int iy_ = yy + kh_ - 1, ix_ = xx + kw_ - 1;                     \
        const bool ok_ = vm && (iy_ >= 0) && (iy_ < FHH) && (ix_ >= 0) && (ix_ < FWW); \
        const float* ap_ = x + ((size_t)(b * CIN + ci0_ + t6)) * NPIX + iy_ * FWW + ix_; \
        _Pragma("unroll")                                                     \
        for (int r = 0; r < 8; ++r) {                                         \
            float v_ = 0.f;                                                   \
            if (ok_) v_ = ap_[(size_t)r * 4 * NPIX];                          \
            VA[r] = v_;                                                       \
        }                                                                     \
        const float4* wp_ = (const float4*)(Wt + (size_t)(((KC) << 5) + bk2) * CMID + n0 + bn2); \
        VB0 = wp_[0];                                                         \
        VB1 = wp_[2048];                                                      \
    } while (0)

#define WRITE_TILE(BUF, VA, VB0, VB1) do {                                    \
        _Pragma("unroll")                                                     \
        for (int r = 0; r < 8; ++r)                                           \
            As[(BUF) * ASZ + (t6 + r * 4) * 72 + mm] = VA[r];                 \
        *(float4*)&Bs[(BUF) * ASZ + bk2 * 72 + bn2] = VB0;                    \
        *(float4*)&Bs[(BUF) * ASZ + (bk2 + 16) * 72 + bn2] = VB1;             \
    } while (0)

#define MFMA_PHASE(BUF) do {                                                  \
        _Pragma("unroll")                                                     \
        for (int ks = 0; ks < 8; ++ks) {                                      \
            double a0 = (double)aBase[(BUF) * ASZ + ks * 288];                \
            double a1 = (double)aBase[(BUF) * ASZ + ks * 288 + 16];           \
            double b0 = (double)bBase[(BUF) * ASZ + ks * 288];                \
            double b1 = (double)bBase[(BUF) * ASZ + ks * 288 + 16];           \
            acc[0][0] = __builtin_amdgcn_mfma_f64_16x16x4f64(a0, b0, acc[0][0], 0, 0, 0); \
            acc[0][1] = __builtin_amdgcn_mfma_f64_16x16x4f64(a0, b1, acc[0][1], 0, 0, 0); \
            acc[1][0] = __builtin_amdgcn_mfma_f64_16x16x4f64(a1, b0, acc[1][0], 0, 0, 0); \
            acc[1][1] = __builtin_amdgcn_mfma_f64_16x16x4f64(a1, b1, acc[1][1], 0, 0, 0); \
        }                                                                     \
    } while (0)

    float va[8]; float4 vb0, vb1;
    float wa[8]; float4 wb0, wb1;
    STAGE_REGS(0, va, vb0, vb1);
    WRITE_TILE(0, va, vb0, vb1);
    __syncthreads();

    for (int kc = 0; kc < 288; kc += 2) {
        // iter kc (buffer 0)
        STAGE_REGS(kc + 1, wa, wb0, wb1);
        MFMA_PHASE(0);
        WRITE_TILE(1, wa, wb0, wb1);
        __syncthreads();
        // iter kc+1 (buffer 1)
        if (kc + 2 < 288) {
            STAGE_REGS(kc + 2, va, vb0, vb1);
            MFMA_PHASE(1);
            WRITE_TILE(0, va, vb0, vb1);
            __syncthreads();
        } else {
            MFMA_PHASE(1);
        }
    }
#undef STAGE_REGS
#undef WRITE_TILE
#undef MFMA_PHASE

    // epilogue through probed D mapping
#pragma unroll
    for (int mi = 0; mi < 2; ++mi) {
#pragma unroll
        for (int nj = 0; nj < 2; ++nj) {
#pragma unroll
            for (int r = 0; r < 4; ++r) {
                int mg  = m0 + wm * 32 + mi * 16 + dRow[r];
                int col = n0 + wn * 32 + nj * 16 + dCol[r];
                if (mg < M_TOT)
                    feat[(size_t)mg * CMID + col] =
                        fmax(acc[mi][nj][r] + (double)bconv[col], 0.0);
            }
        }
    }
}

// K2: 1x1 convs (cls 18 + bbox 36 as 54 outputs), fp64. featD NHWC -> out54D[m][64]
__global__ __launch_bounds__(256) void conv1x1_kernel(
    const double* __restrict__ feat, const double* __restrict__ Wt2pD,
    const float* __restrict__ bcls, const float* __restrict__ bbx,
    double* __restrict__ out54) {
    __shared__ double As[4 * 512];
    __shared__ double Bsh[64 * 64];
    int tid = threadIdx.x;
    int m0 = blockIdx.x * 4;
    for (int off = tid; off < 2048; off += 256) As[off] = feat[(size_t)m0 * CMID + off];
    int p = tid >> 6, n = tid & 63;
    double acc = 0.0;
    for (int c = 0; c < 8; ++c) {
        __syncthreads();
        for (int off = tid; off < 4096; off += 256) Bsh[off] = Wt2pD[c * 4096 + off];
        __syncthreads();
        const double* ap = &As[p * 512 + c * 64];
#pragma unroll 8
        for (int k2 = 0; k2 < 64; ++k2) acc = fma(ap[k2], Bsh[k2 * 64 + n], acc);
    }
    if (n < 54) {
        double bias = (double)((n < 18) ? bcls[n] : bbx[n - 18]);
        out54[(size_t)(m0 + p) * 64 + n] = acc + bias;
    }
}

// K2b: softmax-pair score + bbox_transform_inv + clip, all fp64
__global__ void proposals_kernel(const double* __restrict__ out54, const float* __restrict__ iminfo,
                                 double* __restrict__ scoresD, double* __restrict__ propsD) {
    int gid = blockIdx.x * 256 + threadIdx.x;
    if (gid >= BATCH * NSC) return;
    int b = gid / NSC;
    int rem = gid - b * NSC;
    int p = rem / 9;
    int a = rem - p * 9;
    int y = p / FWW, x = p - y * FWW;
    int m = b * NPIX + p;
    const double* row = out54 + (size_t)m * 64;
    double s0 = row[a], s1 = row[9 + a];
    double mx = fmax(s0, s1);
    double e0 = exp(s0 - mx), e1 = exp(s1 - mx);
    scoresD[gid] = e1 / (e0 + e1);
    double dx = row[18 + 4 * a], dy = row[19 + 4 * a], dw = row[20 + 4 * a], dh = row[21 + 4 * a];
    double ax1 = x * 16.0 + ANCX1[a], ay1 = y * 16.0 + ANCY1[a];
    double ax2 = x * 16.0 + ANCX2[a], ay2 = y * 16.0 + ANCY2[a];
    double w = ax2 - ax1 + 1.0, h = ay2 - ay1 + 1.0;
    double cx = ax1 + 0.5 * w, cy = ay1 + 0.5 * h;
    double px = dx * w + cx, py = dy * h + cy;
    double pw = exp(dw) * w, ph = exp(dh) * h;
    double imh = (double)iminfo[b * 3 + 0], imw = (double)iminfo[b * 3 + 1];
    double x1 = fmin(fmax(px - 0.5 * pw, 0.0), imw - 1.0);
    double y1 = fmin(fmax(py - 0.5 * ph, 0.0), imh - 1.0);
    double x2 = fmin(fmax(px + 0.5 * pw, 0.0), imw - 1.0);
    double y2 = fmin(fmax(py + 0.5 * ph, 0.0), imh - 1.0);
    double* o = propsD + (size_t)gid * 4;
    o[0] = x1; o[1] = y1; o[2] = x2; o[3] = y2;
}

// K3: exact top-2000, stable lower-index ties. key = (double_score_bits & ~0x7FFF) | (~i & 0x7FFF)
__global__ __launch_bounds__(256) void select_kernel(const double* __restrict__ scoresD,
                                                     const double* __restrict__ propsD,
                                                     double* __restrict__ boxesD) {
    __shared__ unsigned int hist4[4][256];
    __shared__ unsigned int histf[256];
    __shared__ unsigned long long keys[2048];
    __shared__ unsigned long long sh_thr;
    __shared__ int sh_need;
    __shared__ int cnt;
    const int b = blockIdx.x, tid = threadIdx.x;
    const int w4 = tid >> 6;
    const double* sc = scoresD + (size_t)b * NSC;

    unsigned long long prefix = 0ull;
    int need = PRE_N;
    for (int d = 7; d >= 0; --d) {
        for (int z = tid; z < 1024; z += 256) ((unsigned int*)hist4)[z] = 0u;
        __syncthreads();
        const int shift = d * 8;
        const unsigned long long maskAbove = (d == 7) ? 0ull : (~0ull << (shift + 8));
        for (int i = tid; i < NSC; i += 256) {
            unsigned long long sb = (unsigned long long)__double_as_longlong(sc[i]);
            unsigned long long key = (sb & ~0x7FFFull) | (unsigned long long)((~i) & 0x7FFF);
            if (((key ^ prefix) & maskAbove) == 0ull)
                atomicAdd(&hist4[w4][(unsigned int)(key >> shift) & 255u], 1u);
        }
        __syncthreads();
        histf[tid] = hist4[0][tid] + hist4[1][tid] + hist4[2][tid] + hist4[3][tid];
        __syncthreads();
        if (tid == 0) {
            int acc = 0, v = 255;
            for (; v > 0; --v) {
                int c = (int)histf[v];
                if (acc + c >= need) break;
                acc += c;
            }
            sh_thr = prefix | ((unsigned long long)(unsigned int)v << shift);
            sh_need = need - acc;
        }
        __syncthreads();
        prefix = sh_thr;
        need = sh_need;
        __syncthreads();
    }
    if (tid == 0) cnt = 0;
    __syncthreads();
    for (int i = tid; i < NSC; i += 256) {
        unsigned long long sb = (unsigned long long)__double_as_longlong(sc[i]);
        unsigned long long key = (sb & ~0x7FFFull) | (unsigned long long)((~i) & 0x7FFF);
        if (key >= prefix) {
            int slot = atomicAdd(&cnt, 1);
            if (slot < 2048) keys[slot] = key;
        }
    }
    __syncthreads();
    int c0 = cnt;
    for (int i = tid; i < 2048; i += 256)
        if (i >= c0) keys[i] = 0ull;
    for (int k2 = 2; k2 <= 2048; k2 <<= 1)
        for (int j = k2 >> 1; j > 0; j >>= 1) {
            __syncthreads();
            for (int i = tid; i < 2048; i += 256) {
                int l = i ^ j;
                if (l > i) {
                    unsigned long long a = keys[i], c = keys[l];
                    bool up = (i & k2) == 0;
                    if (up ? (a < c) : (a > c)) { keys[i] = c; keys[l] = a; }
                }
            }
        }
    __syncthreads();
    const double* pr = propsD + (size_t)b * NSC * 4;
    double* bs = boxesD + (size_t)b * PRE_N * 4;
    for (int r = tid; r < PRE_N; r += 256) {
        int idx = (int)((~keys[r]) & 0x7FFF);
        if (idx >= NSC) idx = 0;
        bs[r * 4 + 0] = pr[(size_t)idx * 4 + 0];
        bs[r * 4 + 1] = pr[(size_t)idx * 4 + 1];
        bs[r * 4 + 2] = pr[(size_t)idx * 4 + 2];
        bs[r * 4 + 3] = pr[(size_t)idx * 4 + 3];
    }
}

// K4a: fp64 suppression bitmask. Interleaved: word w (0..31), bit t -> j = t*32 + w.
__global__ __launch_bounds__(256) void iou_mask_kernel(const double* __restrict__ boxesD,
                                                       unsigned long long* __restrict__ supmask) {
    __shared__ double bx[PRE_N * 4];
    int b = blockIdx.x;
    int i0 = blockIdx.y * 80;
    const double* src = boxesD + (size_t)b * PRE_N * 4;
    for (int o = threadIdx.x; o < PRE_N * 4; o += 256) bx[o] = src[o];
    __syncthreads();
    int ty = threadIdx.x >> 5, jw = threadIdx.x & 31;
    for (int ii = ty; ii < 80; ii += 8) {
        int i = i0 + ii;
        double bix1 = bx[i * 4 + 0], biy1 = bx[i * 4 + 1], bix2 = bx[i * 4 + 2], biy2 = bx[i * 4 + 3];
        double areai = (bix2 - bix1 + 1.0) * (biy2 - biy1 + 1.0);
        unsigned long long bits = 0ull;
        for (int t = 0; t < 64; ++t) {
            int j = t * 32 + jw;
            if (j > i && j < PRE_N) {
                double bjx1 = bx[j * 4 + 0], bjy1 = bx[j * 4 + 1], bjx2 = bx[j * 4 + 2], bjy2 = bx[j * 4 + 3];
                double iw = fmin(bix2, bjx2) - fmax(bix1, bjx1) + 1.0; iw = fmax(iw, 0.0);
                double ih = fmin(biy2, bjy2) - fmax(biy1, bjy1) + 1.0; ih = fmax(ih, 0.0);
                double inter = iw * ih;
                double areaj = (bjx2 - bjx1 + 1.0) * (bjy2 - bjy1 + 1.0);
                double iou = inter / (areai + areaj - inter);
                if (iou > 0.7) bits |= (1ull << t);
            }
        }
        supmask[((size_t)b * PRE_N + i) * 32 + jw] = bits;
    }
}

// K4b: sequential greedy suppression + first-300-kept (stable fill) + fp32 output
__global__ void nms_final_kernel(const unsigned long long* __restrict__ supmask,
                                 const double* __restrict__ boxesD,
                                 float* __restrict__ out) {
    int b = blockIdx.x;
    int lane = threadIdx.x;     // 64 threads
    int w = lane & 31;
    const unsigned long long* mask = supmask + (size_t)b * PRE_N * 32;
    int nbits = (w < 16) ? 63 : 62;
    unsigned long long kw = (1ull << nbits) - 1ull;
    unsigned long long rr[16];
#pragma unroll
    for (int d2 = 0; d2 < 16; ++d2) rr[d2] = mask[d2 * 32 + w];
    for (int i = 0; i < PRE_N; i += 16) {
#pragma unroll
        for (int u = 0; u < 16; ++u) {
            int ii = i + u;
            unsigned long long rcur = rr[u];
            int ip = ii + 16;
            rr[u] = (ip < PRE_N) ? mask[ip * 32 + w] : 0ull;
            unsigned long long kword = __shfl(kw, ii & 31);
            if ((kword >> (ii >> 5)) & 1ull) kw &= ~rcur;
        }
    }
    __shared__ unsigned long long keepw[32];
    __shared__ int pos[POST_N];
    if (lane < 32) keepw[lane] = kw;
    __syncthreads();
    if (lane == 0) {
        int c2 = 0;
        for (int j = 0; j < PRE_N && c2 < POST_N; ++j)
            if ((keepw[j & 31] >> (j >> 5)) & 1ull) pos[c2++] = j;
        for (int j = 0; j < PRE_N && c2 < POST_N; ++j)
            if (!((keepw[j & 31] >> (j >> 5)) & 1ull)) pos[c2++] = j;
    }
    __syncthreads();
    for (int r = lane; r < POST_N; r += 64) {
        int p = pos[r];
        const double* bxp = boxesD + ((size_t)b * PRE_N + p) * 4;
        float* o = out + ((size_t)b * POST_N + r) * 5;
        o[0] = (float)b; o[1] = (float)bxp[0]; o[2] = (float)bxp[1];
        o[3] = (float)bxp[2]; o[4] = (float)bxp[3];
    }
    if (b == 0 && lane == 0) { out[BATCH * POST_N * 5] = 0.f; out[BATCH * POST_N * 5 + 1] = 0.f; }
}

extern "C" void kernel_launch(void* const* d_in, const int* in_sizes, int n_in,
                              void* d_out, int out_size, void* d_ws, size_t ws_size,
                              hipStream_t stream) {
    (void)in_sizes; (void)n_in; (void)out_size; (void)ws_size;
    const float* base_feat = (const float*)d_in[0];
    const float* im_info   = (const float*)d_in[1];
    const float* W_conv    = (const float*)d_in[4];
    const float* b_conv    = (const float*)d_in[5];
    const float* W_cls     = (const float*)d_in[6];
    const float* b_cls     = (const float*)d_in[7];
    const float* W_bbox    = (const float*)d_in[8];
    const float* b_bbox    = (const float*)d_in[9];
    float* out = (float*)d_out;

    double* featD   = (double*)d_ws;            // 9,805,824 d
    double* out54D  = featD + 9805824;          // 1,225,728 d
    double* scoresD = out54D + 1225728;         //   172,368 d
    double* propsD  = scoresD + 172368;         //   689,472 d
    double* boxesD  = propsD + 689472;          //    64,000 d
    double* Wt2pD   = boxesD + 64000;           //    32,768 d
    unsigned long long* supmask = (unsigned long long*)(Wt2pD + 32768); // 512,000 u64
    float* Wt       = (float*)(supmask + 512000);                       // 4,718,592 f32
    // tab aliases propsD: probe writes it first; conv3x3 consumes it; propsD is
    // only written later by proposals_kernel — disjoint lifetimes.
    int* tab = (int*)propsD;                    // 768 ints

    mfma_probe_kernel<<<1, 64, 0, stream>>>(tab);
    wt3x3_kernel<<<(K_TOT * CMID + 255) / 256, 256, 0, stream>>>(W_conv, Wt);
    wt1x1_kernel<<<(CMID * 64 + 255) / 256, 256, 0, stream>>>(W_cls, W_bbox, Wt2pD);
    conv3x3_mfma<<<dim3(8, 300), 256, 0, stream>>>(base_feat, Wt, b_conv, tab, featD);
    conv1x1_kernel<<<M_TOT / 4, 256, 0, stream>>>(featD, Wt2pD, b_cls, b_bbox, out54D);
    proposals_kernel<<<(BATCH * NSC + 255) / 256, 256, 0, stream>>>(out54D, im_info, scoresD, propsD);
    select_kernel<<<BATCH, 256, 0, stream>>>(scoresD, propsD, boxesD);
    iou_mask_kernel<<<dim3(BATCH, 25), 256, 0, stream>>>(boxesD, supmask);
    nms_final_kernel<<<BATCH, 64, 0, stream>>>(supmask, boxesD, out);
}